// Round 15
// baseline (191.172 us; speedup 1.0000x reference)
//
#include <hip/hip_runtime.h>
#include <math.h>

#define NN 4096
#define DD 256
#define TT 32
#define GAMMA (1.0f/256.0f)
#define ITERS 10
#define LO_DROP 2        // iterations >= this use f16-only v in the matvec
#define KC  64           // k-chunk in k_build
#define KBP 72           // f16 elems per LDS row in k_build staging (64 + 8 pad)

typedef __attribute__((ext_vector_type(8))) _Float16 f16x8;
typedef __attribute__((ext_vector_type(4))) _Float16 f16x4;
typedef __attribute__((ext_vector_type(2))) _Float16 f16x2;
typedef __attribute__((ext_vector_type(4))) float f32x4;

// ---------------------------------------------------------------- setup: x2 + f16 X; CG init
// blocks [0,1024): x2conv (4 rows each). blocks [1024,1152): cg_init (one (t,c) each, c in 0..3).
__global__ __launch_bounds__(256) void setup(const float* __restrict__ X,
                                             float* __restrict__ x2,
                                             _Float16* __restrict__ Xh,
                                             const float* __restrict__ y,
                                             _Float16* __restrict__ vh,
                                             _Float16* __restrict__ vl,
                                             float* __restrict__ rrp) {
    const int b = blockIdx.x, tid = threadIdx.x;
    const int wid = tid >> 6, lane = tid & 63;
    if (b < 1024) {
        int row = b * 4 + wid;
        const float* xr = X + (size_t)row * DD;
        float4 v = *(const float4*)(xr + lane * 4);
        float s = v.x * v.x + v.y * v.y + v.z * v.z + v.w * v.w;
        #pragma unroll
        for (int o = 32; o; o >>= 1) s += __shfl_down(s, o);
        if (lane == 0) x2[row] = s;
        f16x4 h;
        h[0] = (_Float16)v.x; h[1] = (_Float16)v.y; h[2] = (_Float16)v.z; h[3] = (_Float16)v.w;
        *(f16x4*)(Xh + (size_t)row * DD + lane * 4) = h;
    } else {
        int bb = b - 1024;                    // 0..127
        int t = bb >> 2, c = bb & 3;          // 4 rr-partials per t (matches cupd grid.y = 4)
        float s = 0.f;
        #pragma unroll
        for (int pass = 0; pass < 4; ++pass) {
            int i = c * 1024 + pass * 256 + tid;
            float v = y[(size_t)i * TT + t];
            size_t off = (size_t)t * NN + i;
            _Float16 h = (_Float16)v;
            vh[off] = h; vl[off] = (_Float16)(v - (float)h);
            s += v * v;
        }
        #pragma unroll
        for (int o = 32; o; o >>= 1) s += __shfl_down(s, o);
        __shared__ float red[4];
        if (lane == 0) red[wid] = s;
        __syncthreads();
        if (tid == 0) rrp[t * 4 + c] = red[0] + red[1] + red[2] + red[3];
    }
}

// ---------------------------------------------------------------- K = exp(-g*d2), f16 out
// 256(i) x 256(j) tile, 8 waves (2x4), wave tile 128x64. KC=64 staging.
__global__ __launch_bounds__(512) void k_build(const _Float16* __restrict__ Xh,
                                               const float* __restrict__ x2,
                                               _Float16* __restrict__ Kh) {
    __shared__ _Float16 As[256 * KBP];   // 36864 B
    __shared__ _Float16 Bs[256 * KBP];   // 36864 B
    const int i0 = blockIdx.x * 256, j0 = blockIdx.y * 256;
    const int tid = threadIdx.x;
    const int wid = tid >> 6, lane = tid & 63;
    const int wr = wid >> 2, wc = wid & 3;         // 2 x 4 waves, 128 x 64 each
    const int l15 = lane & 15, l4 = lane >> 4;
    f32x4 acc[8][4] = {};
    for (int kc = 0; kc < DD; kc += KC) {
        __syncthreads();
        #pragma unroll
        for (int s = 0; s < 4; ++s) {             // A: 256 rows x 8 chunks of 8
            int idx = s * 512 + tid;
            int row = idx >> 3, c = idx & 7;
            *(uint4*)(As + row * KBP + c * 8) =
                *(const uint4*)(Xh + (size_t)(i0 + row) * DD + kc + c * 8);
        }
        #pragma unroll
        for (int s = 0; s < 4; ++s) {             // B: 256 rows x 8 chunks of 8
            int idx = s * 512 + tid;
            int row = idx >> 3, c = idx & 7;
            *(uint4*)(Bs + row * KBP + c * 8) =
                *(const uint4*)(Xh + (size_t)(j0 + row) * DD + kc + c * 8);
        }
        __syncthreads();
        #pragma unroll
        for (int kk = 0; kk < 2; ++kk) {
            f16x8 af[8], bfr[4];
            #pragma unroll
            for (int m = 0; m < 8; ++m)
                af[m] = *(const f16x8*)(As + (wr * 128 + m * 16 + l15) * KBP + kk * 32 + l4 * 8);
            #pragma unroll
            for (int n = 0; n < 4; ++n)
                bfr[n] = *(const f16x8*)(Bs + (wc * 64 + n * 16 + l15) * KBP + kk * 32 + l4 * 8);
            #pragma unroll
            for (int m = 0; m < 8; ++m)
                #pragma unroll
                for (int n = 0; n < 4; ++n)
                    acc[m][n] = __builtin_amdgcn_mfma_f32_16x16x32_f16(af[m], bfr[n], acc[m][n], 0, 0, 0);
        }
    }
    #pragma unroll
    for (int m = 0; m < 8; ++m) {
        #pragma unroll
        for (int rg = 0; rg < 4; ++rg) {
            int i = i0 + wr * 128 + m * 16 + l4 * 4 + rg;
            float x2i = x2[i];
            #pragma unroll
            for (int n = 0; n < 4; ++n) {
                int j = j0 + wc * 64 + n * 16 + l15;
                float d2 = fmaxf(x2i + x2[j] - 2.f * acc[m][n][rg], 0.f);
                Kh[(size_t)i * NN + j] = (_Float16)__expf(-GAMMA * d2);
            }
        }
    }
}

// ---------------------------------------------------------------- matvec: part[jb][t][i] = sum_{j in jb} K[i][j]*v[t][j]
// Block = 64 i-rows (4 waves x 16) x JCHT j. USE_LO adds the lo-correction MFMAs.
// Also emits rKvp[t][bid] = sum_{i in blk} rhi[t][i] * (Kv)[t][i]  (hi-only r: 2e-4 alpha jitter, benign)
template<int USE_LO, int NJB, int JCHT>
__global__ __launch_bounds__(256) void matvec_part(const _Float16* __restrict__ Kh,
                                                   const _Float16* __restrict__ vh,
                                                   const _Float16* __restrict__ vl,
                                                   float* __restrict__ part,
                                                   float* __restrict__ rKvp) {
    const int BROWT = JCHT + 8;
    __shared__ __align__(16) _Float16 Bbuf[(1 + USE_LO) * 32 * (JCHT + 8)];
    __shared__ float redb[4][33];
    _Float16* Bh = Bbuf;
    _Float16* Bl = Bbuf + (USE_LO ? 32 * BROWT : 0);
    const int ib = blockIdx.x;                    // 64
    const int jb = blockIdx.y;                    // NJB
    const int bid = jb * 64 + ib;                 // 0..64*NJB
    const int tid = threadIdx.x;
    const int wid = tid >> 6, lane = tid & 63;
    const int l15 = lane & 15, l4 = lane >> 4;
    // stage v: 32 t-rows x JCHT j
    const int CPR = JCHT / 8;                     // 8-elem chunks per row
    #pragma unroll
    for (int s = 0; s < (32 * CPR) / 256; ++s) {
        int c = s * 256 + tid;
        int row = c / CPR, col8 = c % CPR;
        *(uint4*)(Bh + row * BROWT + col8 * 8) =
            *(const uint4*)(vh + (size_t)row * NN + jb * JCHT + col8 * 8);
        if (USE_LO)
            *(uint4*)(Bl + row * BROWT + col8 * 8) =
                *(const uint4*)(vl + (size_t)row * NN + jb * JCHT + col8 * 8);
    }
    __syncthreads();
    const _Float16* Ap  = Kh + (size_t)(ib * 64 + wid * 16 + l15) * NN + jb * JCHT + l4 * 8;
    const _Float16* bhp = Bh + l15 * BROWT + l4 * 8;
    const _Float16* blp = Bl + l15 * BROWT + l4 * 8;
    f32x4 acc0 = {}, acc1 = {};
    #pragma unroll 4
    for (int jc = 0; jc < JCHT; jc += 32) {
        f16x8 a   = *(const f16x8*)(Ap + jc);
        f16x8 bh0 = *(const f16x8*)(bhp + jc);
        f16x8 bh1 = *(const f16x8*)(bhp + 16 * BROWT + jc);
        acc0 = __builtin_amdgcn_mfma_f32_16x16x32_f16(a, bh0, acc0, 0, 0, 0);
        acc1 = __builtin_amdgcn_mfma_f32_16x16x32_f16(a, bh1, acc1, 0, 0, 0);
        if (USE_LO) {
            f16x8 bl0 = *(const f16x8*)(blp + jc);
            f16x8 bl1 = *(const f16x8*)(blp + 16 * BROWT + jc);
            acc0 = __builtin_amdgcn_mfma_f32_16x16x32_f16(a, bl0, acc0, 0, 0, 0);
            acc1 = __builtin_amdgcn_mfma_f32_16x16x32_f16(a, bl1, acc1, 0, 0, 0);
        }
    }
    __syncthreads();                               // done reading Bh/Bl -> reuse as tl
    float* tl = (float*)Bbuf;                      // [4][32][17] floats = 8704 floats
    #pragma unroll
    for (int rg = 0; rg < 4; ++rg) {
        tl[(wid * 32 + l15) * 17 + l4 * 4 + rg]      = acc0[rg];
        tl[(wid * 32 + 16 + l15) * 17 + l4 * 4 + rg] = acc1[rg];
    }
    __syncthreads();
    #pragma unroll
    for (int q = 0; q < 8; ++q) {
        int idx = q * 64 + lane;
        int t = idx >> 4, il = idx & 15;
        int gi = ib * 64 + wid * 16 + il;
        float val = tl[(wid * 32 + t) * 17 + il];
        part[((size_t)jb * TT + t) * NN + gi] = val;
        float cq = (float)vh[(size_t)t * NN + gi] * val;
        #pragma unroll
        for (int o = 8; o; o >>= 1) cq += __shfl_down(cq, o);
        if (il == 0) redb[wid][t] = cq;
    }
    __syncthreads();
    if (tid < 32) {
        float s = 0.f;
        #pragma unroll
        for (int u = 0; u < 4; ++u) s += redb[u][tid];
        rKvp[tid * (64 * NJB) + bid] = s;
    }
}

// ---------------------------------------------------------------- Chronopoulos-Gear update (float2 per thread)
// r stored ONLY as (vh, vl) f16 pairs (repr error ~6e-8). Tracks d = sum_j alpha_j (s_j - p_j);
// last iter: out = d (y_pred = A@x - x = K@x).
template<int NJB>
__global__ __launch_bounds__(512) void cupd(const float* __restrict__ part,
                                            float* __restrict__ p, float* __restrict__ s_,
                                            float* __restrict__ d,
                                            _Float16* __restrict__ vh,
                                            _Float16* __restrict__ vl,
                                            const float* __restrict__ rrp_in,
                                            float* __restrict__ rrp_out,
                                            const float* __restrict__ rKvp,
                                            const float* __restrict__ scal_in,
                                            float* __restrict__ scal_out,
                                            float* __restrict__ out,
                                            int first, int last) {
    const int t = blockIdx.x, c = blockIdx.y, tid = threadIdx.x;
    const int wid = tid >> 6, lane = tid & 63;
    __shared__ float sc2[2];
    __shared__ float red[8];
    if (wid == 0) {
        float rw_ = 0.f;
        #pragma unroll
        for (int u = 0; u < NJB; ++u) rw_ += rKvp[t * (64 * NJB) + u * 64 + lane];
        float rr_ = (lane < 4) ? rrp_in[t * 4 + lane] : 0.f;
        #pragma unroll
        for (int o = 32; o; o >>= 1) { rw_ += __shfl_down(rw_, o); rr_ += __shfl_down(rr_, o); }
        if (lane == 0) {
            float rr = rr_;
            float rw = rw_ + rr;                   // r.w = r.Kv + r.r  (A = K+I)
            float alpha, beta;
            if (first) { beta = 0.f; alpha = rr / rw; }
            else {
                float ap = scal_in[t], rrprev = scal_in[TT + t];
                beta = rr / rrprev;
                alpha = rr / (rw - (beta / ap) * rr);
            }
            sc2[0] = alpha; sc2[1] = beta;
            if (c == 0) { scal_out[t] = alpha; scal_out[TT + t] = rr; }
        }
    }
    __syncthreads();
    const float alpha = sc2[0], beta = sc2[1];
    int i = c * 1024 + tid * 2;
    size_t off = (size_t)t * NN + i;
    float2 sv = {0.f, 0.f};
    #pragma unroll
    for (int b = 0; b < NJB; ++b) {
        float2 pl = *(const float2*)&part[((size_t)b * TT + t) * NN + i];
        sv.x += pl.x; sv.y += pl.y;
    }
    f16x2 hv0 = *(const f16x2*)(vh + off);
    f16x2 lv0 = *(const f16x2*)(vl + off);
    float2 rv = { (float)hv0[0] + (float)lv0[0], (float)hv0[1] + (float)lv0[1] };
    float2 wv = { sv.x + rv.x, sv.y + rv.y };      // w = Kv + r
    float2 pv, sv2;
    if (first) { pv = rv; sv2 = wv; }
    else {
        float2 po = *(const float2*)(p + off);
        float2 so = *(const float2*)(s_ + off);
        pv  = { fmaf(beta, po.x, rv.x), fmaf(beta, po.y, rv.y) };
        sv2 = { fmaf(beta, so.x, wv.x), fmaf(beta, so.y, wv.y) };
    }
    *(float2*)(p + off) = pv;
    *(float2*)(s_ + off) = sv2;
    float2 dn;
    if (first) {
        dn = { alpha * (sv2.x - pv.x), alpha * (sv2.y - pv.y) };
    } else {
        float2 dv = *(const float2*)(d + off);
        dn = { fmaf(alpha, sv2.x - pv.x, dv.x), fmaf(alpha, sv2.y - pv.y, dv.y) };
    }
    *(float2*)(d + off) = dn;
    float2 rn = { rv.x - alpha * sv2.x, rv.y - alpha * sv2.y };
    if (last) {
        out[(size_t)i * TT + t]       = dn.x;      // y_pred = A@x - x = K@x
        out[(size_t)(i + 1) * TT + t] = dn.y;
    } else {
        _Float16 h0 = (_Float16)rn.x, h1 = (_Float16)rn.y;
        f16x2 hn = { h0, h1 };
        f16x2 ln = { (_Float16)(rn.x - (float)h0), (_Float16)(rn.y - (float)h1) };
        *(f16x2*)(vh + off) = hn;
        *(f16x2*)(vl + off) = ln;
    }
    float v = rn.x * rn.x + rn.y * rn.y;
    #pragma unroll
    for (int o = 32; o; o >>= 1) v += __shfl_down(v, o);
    if (lane == 0) red[wid] = v;
    __syncthreads();
    if (tid == 0) {
        float tot = 0.f;
        #pragma unroll
        for (int u = 0; u < 8; ++u) tot += red[u];
        rrp_out[t * 4 + c] = tot;
    }
}

extern "C" void kernel_launch(void* const* d_in, const int* in_sizes, int n_in,
                              void* d_out, int out_size, void* d_ws, size_t ws_size,
                              hipStream_t stream) {
    const float* X = (const float*)d_in[0];   // [N, D]
    const float* y = (const float*)d_in[1];   // [N, T]
    float* out = (float*)d_out;               // [N, T]

    unsigned char* wsb = (unsigned char*)d_ws;
    _Float16* Kh = (_Float16*)wsb;  wsb += (size_t)NN * NN * 2;          // 32 MB
    float* part  = (float*)wsb;     wsb += (size_t)8 * TT * NN * 4;      // 4 MB (max 8 slices)
    float* p     = (float*)wsb;     wsb += (size_t)TT * NN * 4;
    float* s_    = (float*)wsb;     wsb += (size_t)TT * NN * 4;
    float* d     = (float*)wsb;     wsb += (size_t)TT * NN * 4;
    _Float16* vh = (_Float16*)wsb;  wsb += (size_t)TT * NN * 2;
    _Float16* vl = (_Float16*)wsb;  wsb += (size_t)TT * NN * 2;
    _Float16* Xh = (_Float16*)wsb;  wsb += (size_t)NN * DD * 2;          // 2 MB
    float* x2v   = (float*)wsb;     wsb += (size_t)NN * 4;
    float* rrp   = (float*)wsb;     wsb += 256 * 4;                      // 2 slots x 128
    float* rKvp  = (float*)wsb;     wsb += (size_t)TT * 512 * 4;         // 64 KB (max)
    float* scal  = (float*)wsb;     wsb += 128 * 4;                      // 2 slots x 64

    setup<<<1152, 256, 0, stream>>>(X, x2v, Xh, y, vh, vl, rrp);
    k_build<<<dim3(NN / 256, NN / 256), 512, 0, stream>>>(Xh, x2v, Kh);

    for (int j = 0; j < ITERS; ++j) {
        if (j < LO_DROP)
            matvec_part<1, 8, 512><<<dim3(64, 8), 256, 0, stream>>>(Kh, vh, vl, part, rKvp);
        else
            matvec_part<0, 4, 1024><<<dim3(64, 4), 256, 0, stream>>>(Kh, vh, vl, part, rKvp);
        if (j < LO_DROP)
            cupd<8><<<dim3(TT, 4), 512, 0, stream>>>(part, p, s_, d, vh, vl,
                                                     rrp + (j & 1) * 128, rrp + ((j + 1) & 1) * 128,
                                                     rKvp,
                                                     scal + (j & 1) * 64, scal + ((j + 1) & 1) * 64,
                                                     out, j == 0 ? 1 : 0, j == ITERS - 1 ? 1 : 0);
        else
            cupd<4><<<dim3(TT, 4), 512, 0, stream>>>(part, p, s_, d, vh, vl,
                                                     rrp + (j & 1) * 128, rrp + ((j + 1) & 1) * 128,
                                                     rKvp,
                                                     scal + (j & 1) * 64, scal + ((j + 1) & 1) * 64,
                                                     out, j == 0 ? 1 : 0, j == ITERS - 1 ? 1 : 0);
    }
}

// Round 16
// 178.628 us; speedup vs baseline: 1.0702x; 1.0702x over previous
//
#include <hip/hip_runtime.h>
#include <math.h>

#define NN 4096
#define DD 256
#define TT 32
#define GAMMA (1.0f/256.0f)
#define ITERS 10
#define LO_DROP 2        // iterations >= this use f16-only v in the matvec
#define JBP 8            // j-chunks in matvec
#define JCH 512          // j per matvec block
#define BROW (JCH + 8)   // padded LDS row (f16 elems)
#define KC  64           // k-chunk in k_build
#define KBP 72           // f16 elems per LDS row in k_build staging (64 + 8 pad)

typedef __attribute__((ext_vector_type(8))) _Float16 f16x8;
typedef __attribute__((ext_vector_type(4))) _Float16 f16x4;
typedef __attribute__((ext_vector_type(2))) _Float16 f16x2;
typedef __attribute__((ext_vector_type(4))) float f32x4;

// ---------------------------------------------------------------- setup: x2 + f16 X; CG init
// blocks [0,1024): x2conv (4 rows each). blocks [1024,1152): cg_init (one (t,c) each, c in 0..3).
__global__ __launch_bounds__(256) void setup(const float* __restrict__ X,
                                             float* __restrict__ x2,
                                             _Float16* __restrict__ Xh,
                                             const float* __restrict__ y,
                                             _Float16* __restrict__ vh,
                                             _Float16* __restrict__ vl,
                                             float* __restrict__ rrp) {
    const int b = blockIdx.x, tid = threadIdx.x;
    const int wid = tid >> 6, lane = tid & 63;
    if (b < 1024) {
        int row = b * 4 + wid;
        const float* xr = X + (size_t)row * DD;
        float4 v = *(const float4*)(xr + lane * 4);
        float s = v.x * v.x + v.y * v.y + v.z * v.z + v.w * v.w;
        #pragma unroll
        for (int o = 32; o; o >>= 1) s += __shfl_down(s, o);
        if (lane == 0) x2[row] = s;
        f16x4 h;
        h[0] = (_Float16)v.x; h[1] = (_Float16)v.y; h[2] = (_Float16)v.z; h[3] = (_Float16)v.w;
        *(f16x4*)(Xh + (size_t)row * DD + lane * 4) = h;
    } else {
        int bb = b - 1024;                    // 0..127
        int t = bb >> 2, c = bb & 3;          // 4 rr-partials per t (matches cupd grid.y = 4)
        float s = 0.f;
        #pragma unroll
        for (int pass = 0; pass < 4; ++pass) {
            int i = c * 1024 + pass * 256 + tid;
            float v = y[(size_t)i * TT + t];
            size_t off = (size_t)t * NN + i;
            _Float16 h = (_Float16)v;
            vh[off] = h; vl[off] = (_Float16)(v - (float)h);
            s += v * v;
        }
        #pragma unroll
        for (int o = 32; o; o >>= 1) s += __shfl_down(s, o);
        __shared__ float red[4];
        if (lane == 0) red[wid] = s;
        __syncthreads();
        if (tid == 0) rrp[t * 4 + c] = red[0] + red[1] + red[2] + red[3];
    }
}

// ---------------------------------------------------------------- K = exp(-g*d2), f16 out
// 256(i) x 256(j) tile, 8 waves (2x4), wave tile 128x64. KC=64 staging.
__global__ __launch_bounds__(512) void k_build(const _Float16* __restrict__ Xh,
                                               const float* __restrict__ x2,
                                               _Float16* __restrict__ Kh) {
    __shared__ _Float16 As[256 * KBP];   // 36864 B
    __shared__ _Float16 Bs[256 * KBP];   // 36864 B
    const int i0 = blockIdx.x * 256, j0 = blockIdx.y * 256;
    const int tid = threadIdx.x;
    const int wid = tid >> 6, lane = tid & 63;
    const int wr = wid >> 2, wc = wid & 3;         // 2 x 4 waves, 128 x 64 each
    const int l15 = lane & 15, l4 = lane >> 4;
    f32x4 acc[8][4] = {};
    for (int kc = 0; kc < DD; kc += KC) {
        __syncthreads();
        #pragma unroll
        for (int s = 0; s < 4; ++s) {             // A: 256 rows x 8 chunks of 8
            int idx = s * 512 + tid;
            int row = idx >> 3, c = idx & 7;
            *(uint4*)(As + row * KBP + c * 8) =
                *(const uint4*)(Xh + (size_t)(i0 + row) * DD + kc + c * 8);
        }
        #pragma unroll
        for (int s = 0; s < 4; ++s) {             // B: 256 rows x 8 chunks of 8
            int idx = s * 512 + tid;
            int row = idx >> 3, c = idx & 7;
            *(uint4*)(Bs + row * KBP + c * 8) =
                *(const uint4*)(Xh + (size_t)(j0 + row) * DD + kc + c * 8);
        }
        __syncthreads();
        #pragma unroll
        for (int kk = 0; kk < 2; ++kk) {
            f16x8 af[8], bfr[4];
            #pragma unroll
            for (int m = 0; m < 8; ++m)
                af[m] = *(const f16x8*)(As + (wr * 128 + m * 16 + l15) * KBP + kk * 32 + l4 * 8);
            #pragma unroll
            for (int n = 0; n < 4; ++n)
                bfr[n] = *(const f16x8*)(Bs + (wc * 64 + n * 16 + l15) * KBP + kk * 32 + l4 * 8);
            #pragma unroll
            for (int m = 0; m < 8; ++m)
                #pragma unroll
                for (int n = 0; n < 4; ++n)
                    acc[m][n] = __builtin_amdgcn_mfma_f32_16x16x32_f16(af[m], bfr[n], acc[m][n], 0, 0, 0);
        }
    }
    #pragma unroll
    for (int m = 0; m < 8; ++m) {
        #pragma unroll
        for (int rg = 0; rg < 4; ++rg) {
            int i = i0 + wr * 128 + m * 16 + l4 * 4 + rg;
            float x2i = x2[i];
            #pragma unroll
            for (int n = 0; n < 4; ++n) {
                int j = j0 + wc * 64 + n * 16 + l15;
                float d2 = fmaxf(x2i + x2[j] - 2.f * acc[m][n][rg], 0.f);
                Kh[(size_t)i * NN + j] = (_Float16)__expf(-GAMMA * d2);
            }
        }
    }
}

// ---------------------------------------------------------------- matvec: part[jb][t][i] = sum_{j in jb} K[i][j]*v[t][j]
// Block = 64 i-rows (4 waves x 16) x 512 j; grid (64,8) = 512 blocks.
// USE_LO=0: 33 KB LDS -> 4 blocks/CU. Emits rKvp[t][bid] via hi-only r (2e-4 alpha jitter, benign).
template<int USE_LO>
__global__ __launch_bounds__(256) void matvec_part(const _Float16* __restrict__ Kh,
                                                   const _Float16* __restrict__ vh,
                                                   const _Float16* __restrict__ vl,
                                                   float* __restrict__ part,
                                                   float* __restrict__ rKvp) {
    __shared__ __align__(16) _Float16 Bbuf[(1 + USE_LO) * 32 * BROW];   // 33280 or 66560 B
    __shared__ float redb[4][33];
    _Float16* Bh = Bbuf;
    _Float16* Bl = Bbuf + (USE_LO ? 32 * BROW : 0);
    const int ib = blockIdx.x;                    // 64
    const int jb = blockIdx.y;                    // 8
    const int bid = jb * 64 + ib;                 // 0..511
    const int tid = threadIdx.x;
    const int wid = tid >> 6, lane = tid & 63;
    const int l15 = lane & 15, l4 = lane >> 4;
    // stage v: 32 t-rows x 512 j
    #pragma unroll
    for (int s = 0; s < 8; ++s) {
        int c = s * 256 + tid;                    // 2048 chunks of 8 f16
        int row = c >> 6, col8 = c & 63;
        *(uint4*)(Bh + row * BROW + col8 * 8) =
            *(const uint4*)(vh + (size_t)row * NN + jb * JCH + col8 * 8);
        if (USE_LO)
            *(uint4*)(Bl + row * BROW + col8 * 8) =
                *(const uint4*)(vl + (size_t)row * NN + jb * JCH + col8 * 8);
    }
    __syncthreads();
    const _Float16* Ap  = Kh + (size_t)(ib * 64 + wid * 16 + l15) * NN + jb * JCH + l4 * 8;
    const _Float16* bhp = Bh + l15 * BROW + l4 * 8;
    const _Float16* blp = Bl + l15 * BROW + l4 * 8;
    f32x4 acc0 = {}, acc1 = {};
    #pragma unroll 4
    for (int jc = 0; jc < JCH; jc += 32) {
        f16x8 a   = *(const f16x8*)(Ap + jc);
        f16x8 bh0 = *(const f16x8*)(bhp + jc);
        f16x8 bh1 = *(const f16x8*)(bhp + 16 * BROW + jc);
        acc0 = __builtin_amdgcn_mfma_f32_16x16x32_f16(a, bh0, acc0, 0, 0, 0);
        acc1 = __builtin_amdgcn_mfma_f32_16x16x32_f16(a, bh1, acc1, 0, 0, 0);
        if (USE_LO) {
            f16x8 bl0 = *(const f16x8*)(blp + jc);
            f16x8 bl1 = *(const f16x8*)(blp + 16 * BROW + jc);
            acc0 = __builtin_amdgcn_mfma_f32_16x16x32_f16(a, bl0, acc0, 0, 0, 0);
            acc1 = __builtin_amdgcn_mfma_f32_16x16x32_f16(a, bl1, acc1, 0, 0, 0);
        }
    }
    __syncthreads();                               // done reading Bh/Bl -> reuse as tl
    float* tl = (float*)Bbuf;                      // [4][32][17] floats
    #pragma unroll
    for (int rg = 0; rg < 4; ++rg) {
        tl[(wid * 32 + l15) * 17 + l4 * 4 + rg]      = acc0[rg];
        tl[(wid * 32 + 16 + l15) * 17 + l4 * 4 + rg] = acc1[rg];
    }
    __syncthreads();
    #pragma unroll
    for (int q = 0; q < 8; ++q) {
        int idx = q * 64 + lane;
        int t = idx >> 4, il = idx & 15;
        int gi = ib * 64 + wid * 16 + il;
        float val = tl[(wid * 32 + t) * 17 + il];
        part[((size_t)jb * TT + t) * NN + gi] = val;
        float cq = (float)vh[(size_t)t * NN + gi] * val;
        #pragma unroll
        for (int o = 8; o; o >>= 1) cq += __shfl_down(cq, o);
        if (il == 0) redb[wid][t] = cq;
    }
    __syncthreads();
    if (tid < 32) {
        float s = 0.f;
        #pragma unroll
        for (int u = 0; u < 4; ++u) s += redb[u][tid];
        rKvp[tid * 512 + bid] = s;
    }
}

// ---------------------------------------------------------------- Chronopoulos-Gear update (float2 per thread)
// r stored ONLY as (vh, vl) f16 pairs (repr error ~6e-8). Tracks d = sum_j alpha_j (s_j - p_j);
// last iter: out = d (y_pred = A@x - x = K@x).
__global__ __launch_bounds__(512) void cupd(const float* __restrict__ part,
                                            float* __restrict__ p, float* __restrict__ s_,
                                            float* __restrict__ d,
                                            _Float16* __restrict__ vh,
                                            _Float16* __restrict__ vl,
                                            const float* __restrict__ rrp_in,
                                            float* __restrict__ rrp_out,
                                            const float* __restrict__ rKvp,
                                            const float* __restrict__ scal_in,
                                            float* __restrict__ scal_out,
                                            float* __restrict__ out,
                                            int first, int last) {
    const int t = blockIdx.x, c = blockIdx.y, tid = threadIdx.x;
    const int wid = tid >> 6, lane = tid & 63;
    __shared__ float sc2[2];
    __shared__ float red[8];
    if (wid == 0) {
        float rw_ = 0.f;
        #pragma unroll
        for (int u = 0; u < 8; ++u) rw_ += rKvp[t * 512 + u * 64 + lane];
        float rr_ = (lane < 4) ? rrp_in[t * 4 + lane] : 0.f;
        #pragma unroll
        for (int o = 32; o; o >>= 1) { rw_ += __shfl_down(rw_, o); rr_ += __shfl_down(rr_, o); }
        if (lane == 0) {
            float rr = rr_;
            float rw = rw_ + rr;                   // r.w = r.Kv + r.r  (A = K+I)
            float alpha, beta;
            if (first) { beta = 0.f; alpha = rr / rw; }
            else {
                float ap = scal_in[t], rrprev = scal_in[TT + t];
                beta = rr / rrprev;
                alpha = rr / (rw - (beta / ap) * rr);
            }
            sc2[0] = alpha; sc2[1] = beta;
            if (c == 0) { scal_out[t] = alpha; scal_out[TT + t] = rr; }
        }
    }
    __syncthreads();
    const float alpha = sc2[0], beta = sc2[1];
    int i = c * 1024 + tid * 2;
    size_t off = (size_t)t * NN + i;
    float2 sv = {0.f, 0.f};
    #pragma unroll
    for (int b = 0; b < JBP; ++b) {
        float2 pl = *(const float2*)&part[((size_t)b * TT + t) * NN + i];
        sv.x += pl.x; sv.y += pl.y;
    }
    f16x2 hv0 = *(const f16x2*)(vh + off);
    f16x2 lv0 = *(const f16x2*)(vl + off);
    float2 rv = { (float)hv0[0] + (float)lv0[0], (float)hv0[1] + (float)lv0[1] };
    float2 wv = { sv.x + rv.x, sv.y + rv.y };      // w = Kv + r
    float2 pv, sv2;
    if (first) { pv = rv; sv2 = wv; }
    else {
        float2 po = *(const float2*)(p + off);
        float2 so = *(const float2*)(s_ + off);
        pv  = { fmaf(beta, po.x, rv.x), fmaf(beta, po.y, rv.y) };
        sv2 = { fmaf(beta, so.x, wv.x), fmaf(beta, so.y, wv.y) };
    }
    *(float2*)(p + off) = pv;
    *(float2*)(s_ + off) = sv2;
    float2 dn;
    if (first) {
        dn = { alpha * (sv2.x - pv.x), alpha * (sv2.y - pv.y) };
    } else {
        float2 dv = *(const float2*)(d + off);
        dn = { fmaf(alpha, sv2.x - pv.x, dv.x), fmaf(alpha, sv2.y - pv.y, dv.y) };
    }
    *(float2*)(d + off) = dn;
    float2 rn = { rv.x - alpha * sv2.x, rv.y - alpha * sv2.y };
    if (last) {
        out[(size_t)i * TT + t]       = dn.x;      // y_pred = A@x - x = K@x
        out[(size_t)(i + 1) * TT + t] = dn.y;
    } else {
        _Float16 h0 = (_Float16)rn.x, h1 = (_Float16)rn.y;
        f16x2 hn = { h0, h1 };
        f16x2 ln = { (_Float16)(rn.x - (float)h0), (_Float16)(rn.y - (float)h1) };
        *(f16x2*)(vh + off) = hn;
        *(f16x2*)(vl + off) = ln;
    }
    float v = rn.x * rn.x + rn.y * rn.y;
    #pragma unroll
    for (int o = 32; o; o >>= 1) v += __shfl_down(v, o);
    if (lane == 0) red[wid] = v;
    __syncthreads();
    if (tid == 0) {
        float tot = 0.f;
        #pragma unroll
        for (int u = 0; u < 8; ++u) tot += red[u];
        rrp_out[t * 4 + c] = tot;
    }
}

extern "C" void kernel_launch(void* const* d_in, const int* in_sizes, int n_in,
                              void* d_out, int out_size, void* d_ws, size_t ws_size,
                              hipStream_t stream) {
    const float* X = (const float*)d_in[0];   // [N, D]
    const float* y = (const float*)d_in[1];   // [N, T]
    float* out = (float*)d_out;               // [N, T]

    unsigned char* wsb = (unsigned char*)d_ws;
    _Float16* Kh = (_Float16*)wsb;  wsb += (size_t)NN * NN * 2;          // 32 MB
    float* part  = (float*)wsb;     wsb += (size_t)JBP * TT * NN * 4;    // 4 MB
    float* p     = (float*)wsb;     wsb += (size_t)TT * NN * 4;
    float* s_    = (float*)wsb;     wsb += (size_t)TT * NN * 4;
    float* d     = (float*)wsb;     wsb += (size_t)TT * NN * 4;
    _Float16* vh = (_Float16*)wsb;  wsb += (size_t)TT * NN * 2;
    _Float16* vl = (_Float16*)wsb;  wsb += (size_t)TT * NN * 2;
    _Float16* Xh = (_Float16*)wsb;  wsb += (size_t)NN * DD * 2;          // 2 MB
    float* x2v   = (float*)wsb;     wsb += (size_t)NN * 4;
    float* rrp   = (float*)wsb;     wsb += 256 * 4;                      // 2 slots x 128
    float* rKvp  = (float*)wsb;     wsb += (size_t)TT * 512 * 4;         // 64 KB
    float* scal  = (float*)wsb;     wsb += 128 * 4;                      // 2 slots x 64

    setup<<<1152, 256, 0, stream>>>(X, x2v, Xh, y, vh, vl, rrp);
    k_build<<<dim3(NN / 256, NN / 256), 512, 0, stream>>>(Xh, x2v, Kh);

    for (int j = 0; j < ITERS; ++j) {
        if (j < LO_DROP)
            matvec_part<1><<<dim3(64, 8), 256, 0, stream>>>(Kh, vh, vl, part, rKvp);
        else
            matvec_part<0><<<dim3(64, 8), 256, 0, stream>>>(Kh, vh, vl, part, rKvp);
        cupd<<<dim3(TT, 4), 512, 0, stream>>>(part, p, s_, d, vh, vl,
                                              rrp + (j & 1) * 128, rrp + ((j + 1) & 1) * 128,
                                              rKvp,
                                              scal + (j & 1) * 64, scal + ((j + 1) & 1) * 64,
                                              out, j == 0 ? 1 : 0, j == ITERS - 1 ? 1 : 0);
    }
}